// Round 8
// baseline (496.262 us; speedup 1.0000x reference)
//
#include <hip/hip_runtime.h>
#include <hip/hip_bf16.h>
#include <stdint.h>

// Conv2d 3x3 s1 p1: x (32,128,56,56) f32, w (256,128,3,3) f32, bias (256,), out (32,256,56,56) f32.
// bf16 MFMA implicit GEMM, ic-major K (k = ic*9 + kh*3 + kw).
// Round 8: round-7 occupancy-first structure with DETERMINISTIC vmem counts:
// B loads are 8x inline-asm global_load_dwordx3 (no compiler merging), so counted vmcnt is exact:
//   at writeB: outstanding = 8 B(kb) + 4 A(kb) -> vmcnt(4) retires exactly B(kb)
//   before MFMA barrier: outstanding = 4 A(kb) + 8 B(kb+1) -> vmcnt(8) retires exactly A(kb)

#define CB    32
#define CIC   128
#define CH    56
#define CW    56
#define COC   256
#define CK    1152
#define PLANES (CB*CIC)                 // 4096
#define PH    58
#define PW    64
#define PLANE_SZ (PH*PW)                // 3712
#define KB_STEPS (CK/64)                // 18
#define WT_SLAB (COC*64)                // 16384 elems per K-step slab
#define XS_ELEMS (PLANES*PLANE_SZ+512)  // tail pad, zero-filled
#define NPLANE_D 475136                 // 128*3712 (one image's planes)

#define FENCE asm volatile("" ::: "memory")

typedef short     bf16x8  __attribute__((ext_vector_type(8)));
typedef float     f32x4   __attribute__((ext_vector_type(4)));
typedef unsigned short u16x8 __attribute__((ext_vector_type(8)));
typedef uint32_t  u32x3   __attribute__((ext_vector_type(3)));

// ---------------- pad + bf16 cast: x -> xs [4096][58][64] + zero tail ----------------
__global__ __launch_bounds__(256)
void pad_x_kernel(const float* __restrict__ x, ushort* __restrict__ xp, int total4) {
    int t = blockIdx.x * 256 + threadIdx.x;
    if (t >= total4) return;
    int i4 = t * 4;
    int plane = i4 / PLANE_SZ;
    int rem   = i4 - plane * PLANE_SZ;
    int r = rem >> 6;
    int c0 = rem & 63;
    ushort4 v;
    ushort* pv = (ushort*)&v;
#pragma unroll
    for (int j = 0; j < 4; ++j) {
        int c = c0 + j;
        float val = 0.f;
        if (plane < PLANES && r >= 1 && r <= CH && c >= 1 && c <= CW) {
            val = x[((size_t)plane * CH + (r - 1)) * CW + (c - 1)];
        }
        __hip_bfloat16 b = __float2bfloat16(val);
        pv[j] = *(ushort*)&b;
    }
    *(ushort4*)(xp + i4) = v;
}

// ---------------- weight repack: OIHW f32 -> Wt[kb][oc][64] bf16, ic-major K, baked swizzle ----------------
__global__ __launch_bounds__(256)
void repack_wt_kernel(const float* __restrict__ w, ushort* __restrict__ wt) {
    int t = blockIdx.x * 256 + threadIdx.x;
    if (t >= COC * CK) return;
    int oc = t / CK;
    int k  = t - oc * CK;                 // ic-major: source order == dest order
    int kb = k >> 6, kl = k & 63;
    // 16B-chunk XOR swizzle: chunk kl>>3 stored at slot (kl>>3)^(oc&7)
    int pos = kb * WT_SLAB + (oc << 6) + (kl ^ ((oc & 7) << 3));
    __hip_bfloat16 b = __float2bfloat16(w[t]);
    wt[pos] = *(ushort*)&b;
}

// ---------------- async global->LDS helper ----------------
__device__ __forceinline__ void gload_lds16(const void* g, void* l) {
    __builtin_amdgcn_global_load_lds(
        (const __attribute__((address_space(1))) uint32_t*)g,
        (__attribute__((address_space(3))) uint32_t*)l, 16, 0, 0);
}

// ---------------- MFMA implicit-GEMM conv, occupancy-first exact-counted pipeline ----------------
// grid (1792): remapped so XCD d&7 owns images [4*(d&7), 4*(d&7)+4).
// block 256 = 4 waves, block tile 128(oc) x 128(q), wave 64x64, frags 4x4 of 16x16x32.
__global__ __launch_bounds__(256, 4)
void conv_mfma_s(const ushort* __restrict__ wt, const ushort* __restrict__ xs,
                 const float* __restrict__ bias, float* __restrict__ out) {
    __shared__ __align__(16) ushort ldsA[8192];   // [oc_l][k] chunks swizzled slot = chunk ^ (oc_l&7)
    __shared__ __align__(16) ushort ldsB[8192];   // [q_l][k]  chunks swizzled slot = chunk ^ (q_l&7)

    const int tid  = threadIdx.x;
    const int lane = tid & 63;
    const int wid  = tid >> 6;
    const int wm   = wid >> 1, wn = wid & 1;

    // ---- XCD-aware remap: image-mates share an XCD's L2 (bijection on [0,1792)) ----
    const int d    = blockIdx.x;
    const int xcd  = d & 7;
    const int slot = d >> 3;              // 0..223
    const int im4  = slot / 56;           // 0..3
    const int j    = slot - im4 * 56;     // 0..55
    const int n_img = 4 * xcd + im4;
    const int oc0   = (j / 28) * 128;
    const int q0    = (j - (j / 28) * 28) * 128;

    const int ko = tid & 7;        // k-octet owned for B staging
    const int qq = tid >> 3;       // q-quad index 0..31 (q_local = 4*qq + i)

    f32x4 acc[4][4];
#pragma unroll
    for (int m = 0; m < 4; ++m)
#pragma unroll
        for (int n = 0; n < 4; ++n)
#pragma unroll
            for (int e = 0; e < 4; ++e) acc[m][n][e] = 0.f;

    // ---- per-thread B address state: k = kb*64 + ko*8 + r, ic-major walk (+64 per kb) ----
    int off[8], t9[8], kw[8];
    {
        const int nbase = n_img * NPLANE_D + q0 + 4 * qq;
#pragma unroll
        for (int r = 0; r < 8; ++r) {
            int kp  = ko * 8 + r;           // < 64
            int ic  = kp / 9;
            int t   = kp - ic * 9;
            int kh  = t / 3;
            int kwv = t - kh * 3;
            off[r] = nbase + ic * PLANE_SZ + kh * PW + kwv;
            t9[r] = t;
            kw[r] = kwv;
        }
    }

    // ---- precomputed LDS addresses (loop-invariant) ----
    uint32_t wbyte[4];
#pragma unroll
    for (int i = 0; i < 4; ++i) {
        int q = 4 * qq + i;
        wbyte[i] = (uint32_t)(q * 128 + ((ko ^ (q & 7)) << 4));
    }
    uint32_t fr_off[2];            // frag-read swizzled chunk offset (same for A and B)
#pragma unroll
    for (int kk = 0; kk < 2; ++kk) {
        int octet = kk * 4 + (lane >> 4);
        fr_off[kk] = (uint32_t)((octet ^ (lane & 7)) << 4);
    }
    const uint32_t abase = (uint32_t)((wm * 64 + (lane & 15)) * 128);
    const uint32_t bbase = (uint32_t)((wn * 64 + (lane & 15)) * 128);

    // ---- helpers ----
    u32x3 raw[8];                  // in-flight B data (exactly 8 dwordx3 loads)
    int   sh[8];                   // shift snapshot (kw at load time)

    auto loadB = [&]() {           // 8x global_load_dwordx3, saddr form; then advance state
#pragma unroll
        for (int r = 0; r < 8; ++r) {
            uint32_t voff = (uint32_t)(off[r] - kw[r]) * 2u;   // byte offset of aligned a0
            asm volatile("global_load_dwordx3 %0, %1, %2"
                         : "=v"(raw[r])
                         : "v"(voff), "s"(xs)
                         : "memory");
            sh[r] = kw[r];
        }
        // advance k += 64: ic += 7, t9 += 1 (mod 9, ic-carry)
#pragma unroll
        for (int r = 0; r < 8; ++r) {
            bool w9 = (t9[r] == 8);                    // kh 2->0, ic extra +1
            bool w3 = (kw[r] == 2) && !w9;             // kw 2->0, kh+1
            int dlt = w9 ? (PLANE_SZ - 130) : (w3 ? 62 : 1);
            off[r] += 7 * PLANE_SZ + dlt;
            t9[r] = w9 ? 0 : t9[r] + 1;
            kw[r] = (w9 | w3) ? 0 : kw[r] + 1;
        }
    };
    auto stageA = [&](int kbn) {
        const char* src = (const char*)(wt + (size_t)kbn * WT_SLAB + oc0 * 64);
        char* dst = (char*)ldsA;
#pragma unroll
        for (int c = 0; c < 4; ++c) {
            int chunk = (wid * 4 + c) * 1024;
            gload_lds16(src + chunk + lane * 16, dst + chunk);
        }
    };
    auto writeB = [&]() {          // funnel-shift repack from raw (post-vmcnt) + 4x ds_write_b128
        uint32_t px[8], py[8];
#pragma unroll
        for (int r = 0; r < 8; ++r) {
            int s = 16 * sh[r];
            px[r] = (uint32_t)(((((uint64_t)raw[r].y) << 32) | raw[r].x) >> s);
            py[r] = (uint32_t)(((((uint64_t)raw[r].z) << 32) | raw[r].y) >> s);
        }
#pragma unroll
        for (int i = 0; i < 4; ++i) {
            u16x8 vv;
#pragma unroll
            for (int r = 0; r < 8; ++r) {
                uint32_t w32 = (i < 2) ? px[r] : py[r];
                vv[r] = (unsigned short)(w32 >> (16 * (i & 1)));
            }
            *(u16x8*)((char*)ldsB + wbyte[i]) = vv;
        }
    };

    // ---- prologue: B(0) into regs; invariant at loop top: raw=B(kb), 8 outstanding ----
    loadB();

#pragma unroll 1
    for (int kb = 0; kb < KB_STEPS; ++kb) {
        if (kb) {
            asm volatile("s_waitcnt lgkmcnt(0)" ::: "memory");   // own frag reads retired
            __builtin_amdgcn_s_barrier();                        // all waves done reading LDS
            __builtin_amdgcn_sched_barrier(0);
        }
        stageA(kb);                    // +4 gload_lds  (outstanding: 8 B(kb) then 4 A(kb))
        FENCE;
        asm volatile("s_waitcnt vmcnt(4)" ::: "memory");         // retires exactly B(kb)
        __builtin_amdgcn_sched_barrier(0);
#pragma unroll
        for (int r = 0; r < 8; ++r) asm volatile("" : "+v"(raw[r]));   // SSA pin: reads follow wait
        writeB();                      // repack + 4x ds_write_b128
        const bool more = (kb < KB_STEPS - 1);
        if (more) loadB();             // +8 dwordx3 for B(kb+1), stay in flight across barrier
        FENCE;
        if (more) asm volatile("s_waitcnt vmcnt(8) lgkmcnt(0)" ::: "memory");  // retires A(kb)+ds_writes
        else      asm volatile("s_waitcnt vmcnt(0) lgkmcnt(0)" ::: "memory");
        __builtin_amdgcn_s_barrier();
        __builtin_amdgcn_sched_barrier(0);

        // ---- MFMA: 2 k-halves x 16 mfma ----
#pragma unroll
        for (int kk = 0; kk < 2; ++kk) {
            bf16x8 af[4], bfr[4];
#pragma unroll
            for (int m = 0; m < 4; ++m)
                af[m] = *(const bf16x8*)((const char*)ldsA + (abase + m * 2048 + fr_off[kk]));
#pragma unroll
            for (int n = 0; n < 4; ++n)
                bfr[n] = *(const bf16x8*)((const char*)ldsB + (bbase + n * 2048 + fr_off[kk]));
#pragma unroll
            for (int m = 0; m < 4; ++m)
#pragma unroll
                for (int n = 0; n < 4; ++n)
                    acc[m][n] = __builtin_amdgcn_mfma_f32_16x16x32_bf16(af[m], bfr[n], acc[m][n], 0, 0, 0);
        }
    }

    // ---- epilogue: bias + store (discard w >= 56) ----
#pragma unroll
    for (int m = 0; m < 4; ++m) {
        float bv[4];
        int oc_b = oc0 + wm * 64 + m * 16 + (lane >> 4) * 4;
#pragma unroll
        for (int r = 0; r < 4; ++r) bv[r] = bias[oc_b + r];
#pragma unroll
        for (int n = 0; n < 4; ++n) {
            int q_virt = q0 + wn * 64 + n * 16 + (lane & 15);
            int wcol = q_virt & 63;
            if (wcol >= CW) continue;
            int h = q_virt >> 6;
#pragma unroll
            for (int r = 0; r < 4; ++r) {
                int oc = oc_b + r;
                out[(((size_t)n_img * COC + oc) * CH + h) * CW + wcol] = acc[m][n][r] + bv[r];
            }
        }
    }
}

// ---------------- fp32 direct fallback (no workspace needed) ----------------
__global__ __launch_bounds__(256)
void conv3x3_fallback(const float* __restrict__ x, const float* __restrict__ w,
                      const float* __restrict__ bias, float* __restrict__ out) {
    const int ow  = threadIdx.x & 63;
    const int ocg = threadIdx.x >> 6;
    const int oh  = blockIdx.y;
    const int n   = blockIdx.z;
    if (ow >= CW) return;
    const int oc0 = blockIdx.x * 32 + ocg * 8;
    float acc[8];
#pragma unroll
    for (int j = 0; j < 8; ++j) acc[j] = 0.f;
    const float* xn = x + (size_t)n * CIC * CH * CW;
    for (int ic = 0; ic < CIC; ++ic) {
        const float* xc = xn + (size_t)ic * CH * CW;
#pragma unroll
        for (int kh = 0; kh < 3; ++kh) {
            const int ih = oh + kh - 1;
            if ((unsigned)ih >= (unsigned)CH) continue;
            const float* xr = xc + ih * CW;
            const float xm = (ow > 0)      ? xr[ow - 1] : 0.f;
            const float x0 =                 xr[ow];
            const float xp_ = (ow < CW - 1) ? xr[ow + 1] : 0.f;
#pragma unroll
            for (int j = 0; j < 8; ++j) {
                const float* wj = w + (size_t)(oc0 + j) * CK + ic * 9 + kh * 3;
                acc[j] = fmaf(wj[0], xm, acc[j]);
                acc[j] = fmaf(wj[1], x0, acc[j]);
                acc[j] = fmaf(wj[2], xp_, acc[j]);
            }
        }
    }
    const size_t obase = (((size_t)n * COC + oc0) * CH + oh) * CW + ow;
#pragma unroll
    for (int j = 0; j < 8; ++j)
        out[obase + (size_t)j * CH * CW] = acc[j] + bias[oc0 + j];
}

extern "C" void kernel_launch(void* const* d_in, const int* in_sizes, int n_in,
                              void* d_out, int out_size, void* d_ws, size_t ws_size,
                              hipStream_t stream) {
    const float* x    = (const float*)d_in[0];
    const float* w    = (const float*)d_in[1];
    const float* bias = (const float*)d_in[2];
    float* out        = (float*)d_out;

    const size_t xs_off   = 1u << 20;                                   // wt below 1 MB
    const size_t xs_bytes = (size_t)XS_ELEMS * sizeof(ushort);          // ~30.4 MB
    const size_t need     = xs_off + xs_bytes;                          // ~31.4 MB

    if (ws_size < need) {
        dim3 grid(COC / 32, CH, CB);
        conv3x3_fallback<<<grid, 256, 0, stream>>>(x, w, bias, out);
        return;
    }

    ushort* wt  = (ushort*)d_ws;
    ushort* xs0 = (ushort*)((char*)d_ws + xs_off);

    const int total4 = XS_ELEMS / 4;
    pad_x_kernel<<<(total4 + 255) / 256, 256, 0, stream>>>(x, xs0, total4);
    repack_wt_kernel<<<(COC * CK + 255) / 256, 256, 0, stream>>>(w, wt);

    conv_mfma_s<<<dim3(1792), 256, 0, stream>>>(wt, xs0, bias, out);
}

// Round 9
// 172.219 us; speedup vs baseline: 2.8816x; 2.8816x over previous
//
#include <hip/hip_runtime.h>
#include <hip/hip_bf16.h>
#include <stdint.h>

// Conv2d 3x3 s1 p1: x (32,128,56,56) f32, w (256,128,3,3) f32, bias (256,), out (32,256,56,56) f32.
// bf16 MFMA implicit GEMM, ic-major K (k = ic*9 + kh*3 + kw).
// Round 9: round-2's simple 2-barrier loop + all verified fixes:
//   zero-conflict chunk-XOR LDS swizzles (r3), incremental addressing (r5),
//   ic-major + XCD image-grouped locality (r5: FETCH 22 MB), raw-load/late-shift split,
//   __launch_bounds__(256,3): reg cap ~170 >= ~132 needed -> no spill, 3 blocks/CU.

#define CB    32
#define CIC   128
#define CH    56
#define CW    56
#define COC   256
#define CK    1152
#define PLANES (CB*CIC)                 // 4096
#define PH    58
#define PW    64
#define PLANE_SZ (PH*PW)                // 3712
#define KB_STEPS (CK/64)                // 18
#define WT_SLAB (COC*64)                // 16384 elems per K-step slab
#define XS_ELEMS (PLANES*PLANE_SZ+512)  // tail pad, zero-filled
#define NPLANE_D 475136                 // 128*3712 (one image's planes)

typedef short     bf16x8  __attribute__((ext_vector_type(8)));
typedef float     f32x4   __attribute__((ext_vector_type(4)));
typedef unsigned short u16x8 __attribute__((ext_vector_type(8)));

// ---------------- pad + bf16 cast: x -> xs [4096][58][64] + zero tail ----------------
__global__ __launch_bounds__(256)
void pad_x_kernel(const float* __restrict__ x, ushort* __restrict__ xp, int total4) {
    int t = blockIdx.x * 256 + threadIdx.x;
    if (t >= total4) return;
    int i4 = t * 4;
    int plane = i4 / PLANE_SZ;
    int rem   = i4 - plane * PLANE_SZ;
    int r = rem >> 6;
    int c0 = rem & 63;
    ushort4 v;
    ushort* pv = (ushort*)&v;
#pragma unroll
    for (int j = 0; j < 4; ++j) {
        int c = c0 + j;
        float val = 0.f;
        if (plane < PLANES && r >= 1 && r <= CH && c >= 1 && c <= CW) {
            val = x[((size_t)plane * CH + (r - 1)) * CW + (c - 1)];
        }
        __hip_bfloat16 b = __float2bfloat16(val);
        pv[j] = *(ushort*)&b;
    }
    *(ushort4*)(xp + i4) = v;
}

// ---------------- weight repack: OIHW f32 -> Wt[kb][oc][64] bf16, ic-major K, baked swizzle ----------------
__global__ __launch_bounds__(256)
void repack_wt_kernel(const float* __restrict__ w, ushort* __restrict__ wt) {
    int t = blockIdx.x * 256 + threadIdx.x;
    if (t >= COC * CK) return;
    int oc = t / CK;
    int k  = t - oc * CK;                 // ic-major: source order == dest order
    int kb = k >> 6, kl = k & 63;
    // 16B-chunk XOR swizzle: chunk kl>>3 stored at slot (kl>>3)^(oc&7)
    int pos = kb * WT_SLAB + (oc << 6) + (kl ^ ((oc & 7) << 3));
    __hip_bfloat16 b = __float2bfloat16(w[t]);
    wt[pos] = *(ushort*)&b;
}

// ---------------- async global->LDS helper ----------------
__device__ __forceinline__ void gload_lds16(const void* g, void* l) {
    __builtin_amdgcn_global_load_lds(
        (const __attribute__((address_space(1))) uint32_t*)g,
        (__attribute__((address_space(3))) uint32_t*)l, 16, 0, 0);
}

// ---------------- MFMA implicit-GEMM conv: simple 2-barrier loop, occupancy 3/CU ----------------
// grid (1792): remapped so XCD d&7 owns images [4*(d&7), 4*(d&7)+4).
// block 256 = 4 waves, block tile 128(oc) x 128(q), wave 64x64, frags 4x4 of 16x16x32.
__global__ __launch_bounds__(256, 3)
void conv_mfma_s(const ushort* __restrict__ wt, const ushort* __restrict__ xs,
                 const float* __restrict__ bias, float* __restrict__ out) {
    __shared__ __align__(16) ushort ldsA[8192];   // [oc_l][k] chunks swizzled slot = chunk ^ (oc_l&7)
    __shared__ __align__(16) ushort ldsB[8192];   // [q_l][k]  chunks swizzled slot = chunk ^ (q_l&7)

    const int tid  = threadIdx.x;
    const int lane = tid & 63;
    const int wid  = tid >> 6;
    const int wm   = wid >> 1, wn = wid & 1;

    // ---- XCD-aware remap: image-mates share an XCD's L2 (bijection on [0,1792)) ----
    const int d    = blockIdx.x;
    const int xcd  = d & 7;
    const int slot = d >> 3;              // 0..223
    const int im4  = slot / 56;           // 0..3
    const int j    = slot - im4 * 56;     // 0..55
    const int n_img = 4 * xcd + im4;
    const int oc0   = (j / 28) * 128;
    const int q0    = (j - (j / 28) * 28) * 128;

    const int ko = tid & 7;        // k-octet owned for B staging
    const int qq = tid >> 3;       // q-quad index 0..31 (q_local = 4*qq + i)

    f32x4 acc[4][4];
#pragma unroll
    for (int m = 0; m < 4; ++m)
#pragma unroll
        for (int n = 0; n < 4; ++n)
#pragma unroll
            for (int e = 0; e < 4; ++e) acc[m][n][e] = 0.f;

    // ---- per-thread B address state: k = kb*64 + ko*8 + r, ic-major walk (+64 per kb) ----
    int off[8], t9[8], kw[8];
    {
        const int nbase = n_img * NPLANE_D + q0 + 4 * qq;
#pragma unroll
        for (int r = 0; r < 8; ++r) {
            int kp  = ko * 8 + r;           // < 64
            int ic  = kp / 9;
            int t   = kp - ic * 9;
            int kh  = t / 3;
            int kwv = t - kh * 3;
            off[r] = nbase + ic * PLANE_SZ + kh * PW + kwv;
            t9[r] = t;
            kw[r] = kwv;
        }
    }

    // ---- precomputed LDS addresses (loop-invariant) ----
    uint32_t wbyte[4];
#pragma unroll
    for (int i = 0; i < 4; ++i) {
        int q = 4 * qq + i;
        wbyte[i] = (uint32_t)(q * 128 + ((ko ^ (q & 7)) << 4));
    }
    uint32_t fr_off[2];            // frag-read swizzled chunk offset (same for A and B)
#pragma unroll
    for (int kk = 0; kk < 2; ++kk) {
        int octet = kk * 4 + (lane >> 4);
        fr_off[kk] = (uint32_t)((octet ^ (lane & 7)) << 4);
    }
    const uint32_t abase = (uint32_t)((wm * 64 + (lane & 15)) * 128);
    const uint32_t bbase = (uint32_t)((wn * 64 + (lane & 15)) * 128);

    // ---- helpers ----
    uint2    braw01[8];            // raw 12B windows (pure loads; shifts deferred to writeB)
    uint32_t braw2[8];

    auto loadB = [&]() {           // pure loads, no dependent ALU (waits sink to writeB)
#pragma unroll
        for (int r = 0; r < 8; ++r) {
            int a0 = off[r] - kw[r];        // 8B-aligned
            braw01[r] = *(const uint2*)(xs + a0);
            braw2[r]  = *(const uint32_t*)(xs + a0 + 4);
        }
    };
    auto writeB = [&]() {          // funnel-shift repack (uses pre-advance kw) + 4x ds_write_b128
        uint32_t px[8], py[8];
#pragma unroll
        for (int r = 0; r < 8; ++r) {
            int s = 16 * kw[r];
            px[r] = (uint32_t)(((((uint64_t)braw01[r].y) << 32) | braw01[r].x) >> s);
            py[r] = (uint32_t)(((((uint64_t)braw2[r])    << 32) | braw01[r].y) >> s);
        }
#pragma unroll
        for (int i = 0; i < 4; ++i) {
            u16x8 vv;
#pragma unroll
            for (int r = 0; r < 8; ++r) {
                uint32_t w32 = (i < 2) ? px[r] : py[r];
                vv[r] = (unsigned short)(w32 >> (16 * (i & 1)));
            }
            *(u16x8*)((char*)ldsB + wbyte[i]) = vv;
        }
    };
    auto advance = [&]() {                  // k += 64: ic += 7, t9 += 1 (mod 9, ic-carry)
#pragma unroll
        for (int r = 0; r < 8; ++r) {
            bool w9 = (t9[r] == 8);                    // kh 2->0, ic extra +1
            bool w3 = (kw[r] == 2) && !w9;             // kw 2->0, kh+1
            int dlt = w9 ? (PLANE_SZ - 130) : (w3 ? 62 : 1);
            off[r] += 7 * PLANE_SZ + dlt;
            t9[r] = w9 ? 0 : t9[r] + 1;
            kw[r] = (w9 | w3) ? 0 : kw[r] + 1;
        }
    };
    auto stageA = [&](int kbn) {
        const char* src = (const char*)(wt + (size_t)kbn * WT_SLAB + oc0 * 64);
        char* dst = (char*)ldsA;
#pragma unroll
        for (int c = 0; c < 4; ++c) {
            int chunk = (wid * 4 + c) * 1024;
            gload_lds16(src + chunk + lane * 16, dst + chunk);
        }
    };

    // ---- main loop: round-2 structure (2 barriers/kb), verified-simple ----
#pragma unroll 1
    for (int kb = 0; kb < KB_STEPS; ++kb) {
        loadB();                       // issue B(kb) loads (overlap prev MFMA + barrier)
        if (kb) __syncthreads();       // all waves done reading LDS(kb-1)
        stageA(kb);                    // 4x gload_lds (A weights, L2-hot)
        writeB();                      // waits for B loads here; repack + ds_write_b128
        advance();
        __syncthreads();               // drains gload_lds + ds_writes

        // ---- MFMA: 2 k-halves x 16 mfma ----
#pragma unroll
        for (int kk = 0; kk < 2; ++kk) {
            bf16x8 af[4], bfr[4];
#pragma unroll
            for (int m = 0; m < 4; ++m)
                af[m] = *(const bf16x8*)((const char*)ldsA + (abase + m * 2048 + fr_off[kk]));
#pragma unroll
            for (int n = 0; n < 4; ++n)
                bfr[n] = *(const bf16x8*)((const char*)ldsB + (bbase + n * 2048 + fr_off[kk]));
#pragma unroll
            for (int m = 0; m < 4; ++m)
#pragma unroll
                for (int n = 0; n < 4; ++n)
                    acc[m][n] = __builtin_amdgcn_mfma_f32_16x16x32_bf16(af[m], bfr[n], acc[m][n], 0, 0, 0);
        }
    }

    // ---- epilogue: bias + store (discard w >= 56) ----
#pragma unroll
    for (int m = 0; m < 4; ++m) {
        float bv[4];
        int oc_b = oc0 + wm * 64 + m * 16 + (lane >> 4) * 4;
#pragma unroll
        for (int r = 0; r < 4; ++r) bv[r] = bias[oc_b + r];
#pragma unroll
        for (int n = 0; n < 4; ++n) {
            int q_virt = q0 + wn * 64 + n * 16 + (lane & 15);
            int wcol = q_virt & 63;
            if (wcol >= CW) continue;
            int h = q_virt >> 6;
#pragma unroll
            for (int r = 0; r < 4; ++r) {
                int oc = oc_b + r;
                out[(((size_t)n_img * COC + oc) * CH + h) * CW + wcol] = acc[m][n][r] + bv[r];
            }
        }
    }
}

// ---------------- fp32 direct fallback (no workspace needed) ----------------
__global__ __launch_bounds__(256)
void conv3x3_fallback(const float* __restrict__ x, const float* __restrict__ w,
                      const float* __restrict__ bias, float* __restrict__ out) {
    const int ow  = threadIdx.x & 63;
    const int ocg = threadIdx.x >> 6;
    const int oh  = blockIdx.y;
    const int n   = blockIdx.z;
    if (ow >= CW) return;
    const int oc0 = blockIdx.x * 32 + ocg * 8;
    float acc[8];
#pragma unroll
    for (int j = 0; j < 8; ++j) acc[j] = 0.f;
    const float* xn = x + (size_t)n * CIC * CH * CW;
    for (int ic = 0; ic < CIC; ++ic) {
        const float* xc = xn + (size_t)ic * CH * CW;
#pragma unroll
        for (int kh = 0; kh < 3; ++kh) {
            const int ih = oh + kh - 1;
            if ((unsigned)ih >= (unsigned)CH) continue;
            const float* xr = xc + ih * CW;
            const float xm = (ow > 0)      ? xr[ow - 1] : 0.f;
            const float x0 =                 xr[ow];
            const float xp_ = (ow < CW - 1) ? xr[ow + 1] : 0.f;
#pragma unroll
            for (int j = 0; j < 8; ++j) {
                const float* wj = w + (size_t)(oc0 + j) * CK + ic * 9 + kh * 3;
                acc[j] = fmaf(wj[0], xm, acc[j]);
                acc[j] = fmaf(wj[1], x0, acc[j]);
                acc[j] = fmaf(wj[2], xp_, acc[j]);
            }
        }
    }
    const size_t obase = (((size_t)n * COC + oc0) * CH + oh) * CW + ow;
#pragma unroll
    for (int j = 0; j < 8; ++j)
        out[obase + (size_t)j * CH * CW] = acc[j] + bias[oc0 + j];
}

extern "C" void kernel_launch(void* const* d_in, const int* in_sizes, int n_in,
                              void* d_out, int out_size, void* d_ws, size_t ws_size,
                              hipStream_t stream) {
    const float* x    = (const float*)d_in[0];
    const float* w    = (const float*)d_in[1];
    const float* bias = (const float*)d_in[2];
    float* out        = (float*)d_out;

    const size_t xs_off   = 1u << 20;                                   // wt below 1 MB
    const size_t xs_bytes = (size_t)XS_ELEMS * sizeof(ushort);          // ~30.4 MB
    const size_t need     = xs_off + xs_bytes;                          // ~31.4 MB

    if (ws_size < need) {
        dim3 grid(COC / 32, CH, CB);
        conv3x3_fallback<<<grid, 256, 0, stream>>>(x, w, bias, out);
        return;
    }

    ushort* wt  = (ushort*)d_ws;
    ushort* xs0 = (ushort*)((char*)d_ws + xs_off);

    const int total4 = XS_ELEMS / 4;
    pad_x_kernel<<<(total4 + 255) / 256, 256, 0, stream>>>(x, xs0, total4);
    repack_wt_kernel<<<(COC * CK + 255) / 256, 256, 0, stream>>>(w, wt);

    conv_mfma_s<<<dim3(1792), 256, 0, stream>>>(wt, xs0, bias, out);
}